// Round 8
// baseline (75.435 us; speedup 1.0000x reference)
//
#include <hip/hip_runtime.h>

namespace {

constexpr int kC = 32;
constexpr int kD = 512;
constexpr int kB = 512;
constexpr int kN = 1024;               // 2B rows (source ++ target)
constexpr int kCD = kC * kD;           // floats per batch index i
constexpr int KT = kD / 32;            // 16 k-tiles of 32

typedef float f32x4 __attribute__((ext_vector_type(4)));
typedef short s16x8 __attribute__((ext_vector_type(8)));

// pack two f32 to bf16 (RNE) into one u32: a -> low half, b -> high half
__device__ inline unsigned int pack_bf16(float a, float b) {
  unsigned int ua = __float_as_uint(a);
  unsigned int ub = __float_as_uint(b);
  ua += 0x7fffu + ((ua >> 16) & 1u);   // round-to-nearest-even
  ub += 0x7fffu + ((ub >> 16) & 1u);
  return (ua >> 16) | (ub & 0xffff0000u);
}

// Pass 1: fragment-major bf16 layout + row sq.
// Frag(c, r16, ks) = 1KB block at u32 index ((c*64+r16)*16+ks)*256; its 16B
// slot s holds rows 16*r16+(s&15), k-elems ks*32+(s>>4)*8.. (exactly the
// mfma_16x16x32 A/B lane fragment). One wave per (i,c) row: lane ln owns
// d = ln*8.. -> ks=ln>>2, chunk q=ln&3, slot (i&15)+16q.
__global__ void prep_kernel(const float* __restrict__ src,
                            const float* __restrict__ tgt,
                            float* __restrict__ sq,
                            unsigned int* __restrict__ tot2,
                            float* __restrict__ out) {
  if (blockIdx.x == 0 && threadIdx.x == 0) *out = 0.f;
  int gw = (blockIdx.x * blockDim.x + threadIdx.x) >> 6;
  int lane = threadIdx.x & 63;
  int i = gw >> 5;
  int c = gw & 31;
  const float* p = (i < kB ? src + (size_t)i * kCD
                           : tgt + (size_t)(i - kB) * kCD) + c * kD;
  f32x4 v0 = *(const f32x4*)(p + lane * 8);
  f32x4 v1 = *(const f32x4*)(p + lane * 8 + 4);

  uint4 w = make_uint4(pack_bf16(v0.x, v0.y), pack_bf16(v0.z, v0.w),
                       pack_bf16(v1.x, v1.y), pack_bf16(v1.z, v1.w));
  int ks = lane >> 2;
  int q = lane & 3;
  size_t slot16 = ((size_t)(c * 64 + (i >> 4)) * 16 + ks) * 64 +
                  ((i & 15) + 16 * q);
  *(uint4*)(tot2 + slot16 * 4) = w;

  float s = v0.x * v0.x + v0.y * v0.y + v0.z * v0.z + v0.w * v0.w
          + v1.x * v1.x + v1.y * v1.y + v1.z * v1.z + v1.w * v1.w;
#pragma unroll
  for (int o = 32; o > 0; o >>= 1) s += __shfl_down(s, o);
  if (lane == 0) sq[c * kN + i] = s;
}

// Pass 2: one INDEPENDENT wave per (tile(I,J), c). Tile = 128x64 output
// (A row-tiles m=0..7, B col-tiles n=0..3). Triangular cover: J >= 2I; the
// straddle tiles J in {2I, 2I+1} get per-element diag weights. No LDS, no
// barriers: fragments are coalesced 1KB global loads from tot2 (L2-resident,
// channel pinned to XCD via b%8==c%8). Explicit 1-step frag double-buffer.
__launch_bounds__(256, 2)
__global__ void mmd_kernel(const unsigned short* __restrict__ tot2,
                           const float* __restrict__ sq,
                           float* __restrict__ out) {
  const int b = blockIdx.x;
  const int c = b & 31;          // XCD pin
  const int g = b >> 5;          // 0..17
  const int t = threadIdx.x;
  const int lane = t & 63;
  const int wid = t >> 6;

  int p = g * 4 + wid;           // 0..71
  int I = 0;
  while (p >= 16 - 2 * I) { p -= 16 - 2 * I; ++I; }
  const int J = 2 * I + p;       // 0..15

  const s16x8* base = (const s16x8*)tot2;
  const s16x8* Af = base + ((size_t)(c * 64 + I * 8) * 16) * 64 + lane;
  const s16x8* Bf = base + ((size_t)(c * 64 + J * 4) * 16) * 64 + lane;

  f32x4 acc[8][4] = {};
  s16x8 aF[2][8], bF[2][4];

#pragma unroll
  for (int m = 0; m < 8; ++m) aF[0][m] = Af[m * 16 * 64];
#pragma unroll
  for (int n = 0; n < 4; ++n) bF[0][n] = Bf[n * 16 * 64];

#pragma unroll
  for (int ks = 0; ks < KT; ++ks) {
    const int cur = ks & 1, nxt = cur ^ 1;   // compile-time (full unroll)
    if (ks + 1 < KT) {
#pragma unroll
      for (int m = 0; m < 8; ++m) aF[nxt][m] = Af[(m * 16 + ks + 1) * 64];
#pragma unroll
      for (int n = 0; n < 4; ++n) bF[nxt][n] = Bf[(n * 16 + ks + 1) * 64];
    }
#pragma unroll
    for (int m = 0; m < 8; ++m)
#pragma unroll
      for (int n = 0; n < 4; ++n)
        acc[m][n] = __builtin_amdgcn_mfma_f32_16x16x32_bf16(
            aF[cur][m], bF[cur][n], acc[m][n], 0, 0, 0);
  }

  // epilogue: L2 = sq_i + sq_j - 2*cross; 5-sigma kernel via repeated
  // squaring. acc[m][n] reg rI -> row I*128+m*16+(lane>>4)*4+rI,
  // col J*64+n*16+(lane&15)  [verified mapping, rounds 2-7].
  const float sgn = ((I < 4) == (J < 8)) ? 1.f : -1.f;
  const float scale = sgn / 262144.f;      // / B^2
  const float* sqA = sq + c * kN + I * 128;
  const float* sqB = sq + c * kN + J * 64;
  const bool edge = (J <= 2 * I + 1);      // wave-uniform
  const int s4 = lane >> 4, l15 = lane & 15;

  float local = 0.f;
#pragma unroll
  for (int m = 0; m < 8; ++m) {
    float sqa_r[4];
#pragma unroll
    for (int rI = 0; rI < 4; ++rI)
      sqa_r[rI] = sqA[m * 16 + s4 * 4 + rI];
#pragma unroll
    for (int n = 0; n < 4; ++n) {
      float sqb_ = sqB[n * 16 + l15];
#pragma unroll
      for (int rI = 0; rI < 4; ++rI) {
        float L2 = sqa_r[rI] + sqb_ - 2.f * acc[m][n][rI];
        float tt = __expf(L2 * -0.0625f);  // exp(-L2/16)
        float t2 = tt * tt, t4 = t2 * t2, t8 = t4 * t4;
        float sumt = tt + t2 + t4 + t8 + t8 * t8;
        if (edge) {
          int gr = I * 128 + m * 16 + s4 * 4 + rI;
          int gc = J * 64 + n * 16 + l15;
          float w = gr < gc ? 2.f : (gr == gc ? 1.f : 0.f);
          local += w * sumt;
        } else {
          local += 2.f * sumt;
        }
      }
    }
  }
  local *= scale;

  __shared__ float wsum[4];
#pragma unroll
  for (int o = 32; o > 0; o >>= 1) local += __shfl_down(local, o);
  if (lane == 0) wsum[wid] = local;
  __syncthreads();
  if (t == 0)
    atomicAdd(out, wsum[0] + wsum[1] + wsum[2] + wsum[3]);
}

}  // namespace

extern "C" void kernel_launch(void* const* d_in, const int* in_sizes, int n_in,
                              void* d_out, int out_size, void* d_ws,
                              size_t ws_size, hipStream_t stream) {
  const float* src = (const float*)d_in[0];
  const float* tgt = (const float*)d_in[1];
  float* out = (float*)d_out;

  // workspace: [sq: 32*1024 f32 = 128 KiB][tot2 bf16 frags: 32 MiB]
  float* sq = (float*)d_ws;
  unsigned int* tot2 = (unsigned int*)((char*)d_ws + (size_t)kC * kN * 4);

  {
    int blocks = (kN * kC) / 4;   // one wave per (i,c) row, 4 waves/block
    prep_kernel<<<blocks, 256, 0, stream>>>(src, tgt, sq, tot2, out);
  }
  {
    int blocks = 18 * kC;         // 72 tiles x 32 ch / 4 waves = 576
    mmd_kernel<<<blocks, 256, 0, stream>>>((const unsigned short*)tot2, sq, out);
  }
}

// Round 9
// 55.410 us; speedup vs baseline: 1.3614x; 1.3614x over previous
//
#include <hip/hip_runtime.h>

namespace {

constexpr int kC = 32;
constexpr int kD = 512;
constexpr int kB = 512;
constexpr int kN = 1024;               // 2B rows (source ++ target)
constexpr int kCD = kC * kD;           // floats per batch index i
constexpr int BM = 128;                // panel rows
constexpr int BKt = 32;                // K chunk (bf16 elements)
constexpr int KT = kD / BKt;           // 16
constexpr int NG = 20;                 // pair-groups per channel

typedef float f32x4 __attribute__((ext_vector_type(4)));
typedef short s16x8 __attribute__((ext_vector_type(8)));

// 20 groups covering the 36 triangular (ti<=tj) 128-panel pairs; rows with an
// odd pair count get a duplicated last pair (weight 0.5 each).
__device__ __constant__ int gTi[NG] = {0,0,0,0, 1,1,1,1, 2,2,2, 3,3,3, 4,4, 5,5, 6, 7};
__device__ __constant__ int gT0[NG] = {0,2,4,6, 1,3,5,7, 2,4,6, 3,5,7, 4,6, 5,7, 6, 7};
__device__ __constant__ int gT1[NG] = {1,3,5,7, 2,4,6,7, 3,5,7, 4,6,7, 5,7, 6,7, 7, 7};

// pack two f32 to bf16 (RNE) into one u32: a -> low half, b -> high half
__device__ inline unsigned int pack_bf16(float a, float b) {
  unsigned int ua = __float_as_uint(a);
  unsigned int ub = __float_as_uint(b);
  ua += 0x7fffu + ((ua >> 16) & 1u);   // round-to-nearest-even
  ub += 0x7fffu + ((ub >> 16) & 1u);
  return (ua >> 16) | (ub & 0xffff0000u);
}

// Pass 1: tot[c][i][d] = bf16(total[i,c,d]); sq[c*kN+i] = sum_d total^2 (f32).
// One wave per (i,c) row of 512 floats. Also zeroes d_out (replaces memset).
__global__ void prep_kernel(const float* __restrict__ src,
                            const float* __restrict__ tgt,
                            float* __restrict__ sq,
                            unsigned int* __restrict__ tot,
                            float* __restrict__ out) {
  if (blockIdx.x == 0 && threadIdx.x == 0) *out = 0.f;
  int gw = (blockIdx.x * blockDim.x + threadIdx.x) >> 6;
  int lane = threadIdx.x & 63;
  int i = gw >> 5;
  int c = gw & 31;
  const float* p = (i < kB ? src + (size_t)i * kCD
                           : tgt + (size_t)(i - kB) * kCD) + c * kD;
  f32x4 v0 = *(const f32x4*)(p + lane * 8);
  f32x4 v1 = *(const f32x4*)(p + lane * 8 + 4);

  uint4 w = make_uint4(pack_bf16(v0.x, v0.y), pack_bf16(v0.z, v0.w),
                       pack_bf16(v1.x, v1.y), pack_bf16(v1.z, v1.w));
  *(uint4*)(tot + (size_t)(c * kN + i) * (kD / 2) + lane * 4) = w;

  float s = v0.x * v0.x + v0.y * v0.y + v0.z * v0.z + v0.w * v0.w
          + v1.x * v1.x + v1.y * v1.y + v1.z * v1.z + v1.w * v1.w;
#pragma unroll
  for (int o = 32; o > 0; o >>= 1) s += __shfl_down(s, o);
  if (lane == 0) sq[c * kN + i] = s;
}

// Pass 2: block = (group(ti,{tj0,tj1}), c); 512 threads / 8 waves.
// Waves 0-3 compute pair (ti,tj0), waves 4-7 pair (ti,tj1); the A panel is
// staged ONCE per K-step and shared. 3-deep LDS pipeline, counted vmcnt(3),
// one raw barrier per step, setprio around MFMA (R5-verified skeleton).
// LDS layout per 8KB panel-buffer: row r (0..127, 64B), 16B chunk q at byte
// S(r,q) = (r>>1)*128 + (r&1)*64 + (q ^ ((r>>1)&3))*16   [R4/R5-verified].
__launch_bounds__(512, 2)
__global__ void mmd_kernel(const unsigned short* __restrict__ tot,
                           const float* __restrict__ sq,
                           float* __restrict__ out) {
  const int b = blockIdx.x;
  const int c = b & 31;          // b = g*32 + c -> b%8 == c%8 (XCD pin)
  const int g = b >> 5;          // 0..19
  const int ti = gTi[g];
  const int t0 = gT0[g];
  const int t1 = gT1[g];

  __shared__ __align__(16) unsigned short lA[3][BM * BKt];     // 3 x 8KB
  __shared__ __align__(16) unsigned short lB[3][2][BM * BKt];  // 3 x 16KB
  __shared__ float wsum[8];

  const int t = threadIdx.x;
  const int lane = t & 63;
  const int wid = t >> 6;        // 0..7
  const int bsel = wid >> 2;     // which B tile this wave computes
  const int wr = (wid >> 1) & 1; // wave row within 128^2 tile
  const int wc = wid & 1;        // wave col

  const unsigned short* gA  = tot + (size_t)(c * kN + ti * BM) * kD;
  const unsigned short* gB0 = tot + (size_t)(c * kN + t0 * BM) * kD;
  const unsigned short* gB1 = tot + (size_t)(c * kN + t1 * BM) * kD;

  // staging: wave w writes 1KB segment w of each panel (rows 16w..16w+15);
  // lane l's 16B at linear w*1024+l*16 holds row 16w+srow, chunk scch:
  const int srow = ((lane >> 3) << 1) + ((lane >> 2) & 1);
  const int scch = (lane & 3) ^ ((lane >> 3) & 3);

  auto STAGE = [&](int buf, int ks) {
    int r = 16 * wid + srow;
    size_t off = (size_t)r * kD + ks * BKt + scch * 8;
    __builtin_amdgcn_global_load_lds(
        (const __attribute__((address_space(1))) unsigned int*)(gA + off),
        (__attribute__((address_space(3))) unsigned int*)&lA[buf][wid * 512],
        16, 0, 0);
    __builtin_amdgcn_global_load_lds(
        (const __attribute__((address_space(1))) unsigned int*)(gB0 + off),
        (__attribute__((address_space(3))) unsigned int*)&lB[buf][0][wid * 512],
        16, 0, 0);
    __builtin_amdgcn_global_load_lds(
        (const __attribute__((address_space(1))) unsigned int*)(gB1 + off),
        (__attribute__((address_space(3))) unsigned int*)&lB[buf][1][wid * 512],
        16, 0, 0);
  };

  // fragment-read lane offset (bytes): row 16m + (lane&15), k-chunk lane>>4;
  // swizzle term lane-only -> m offsets are compile-time immediates.
  const int l15 = lane & 15;
  const int s4 = lane >> 4;
  const int laneoff = ((l15 >> 1) << 7) + ((l15 & 1) << 6) +
                      ((s4 ^ ((l15 >> 1) & 3)) << 4);

  f32x4 acc[4][4] = {};

  STAGE(0, 0);
  STAGE(1, 1);

#pragma unroll
  for (int ks = 0; ks < KT; ++ks) {
    // wait only for this step's stage (3 instrs/wave remain in flight for
    // the next one); never vmcnt(0) mid-loop (T4).
    if (ks + 1 < KT) asm volatile("s_waitcnt vmcnt(3)" ::: "memory");
    else             asm volatile("s_waitcnt vmcnt(0)" ::: "memory");
    __builtin_amdgcn_sched_barrier(0);
    __builtin_amdgcn_s_barrier();        // raw barrier: no implicit drain

    const int buf = ks % 3;
    const char* Abase = (const char*)lA[buf] + wr * 4096 + laneoff;
    const char* Bbase = (const char*)lB[buf][bsel] + wc * 4096 + laneoff;
    s16x8 aF[4], bF[4];
#pragma unroll
    for (int m = 0; m < 4; ++m) aF[m] = *(const s16x8*)(Abase + m * 1024);
#pragma unroll
    for (int n = 0; n < 4; ++n) bF[n] = *(const s16x8*)(Bbase + n * 1024);

    // overwrites buf (ks+2)%3 == (ks-1)%3: all waves' ks-1 LDS reads were
    // consumed (lgkmcnt before their MFMAs) before crossing this barrier.
    if (ks + 2 < KT) STAGE((ks + 2) % 3, ks + 2);

    __builtin_amdgcn_s_setprio(1);
#pragma unroll
    for (int m = 0; m < 4; ++m)
#pragma unroll
      for (int n = 0; n < 4; ++n)
        acc[m][n] = __builtin_amdgcn_mfma_f32_16x16x32_bf16(
            aF[m], bF[n], acc[m][n], 0, 0, 0);
    __builtin_amdgcn_s_setprio(0);
  }

  // epilogue: L2 = sq_i + sq_j - 2*cross; 5-sigma kernel via repeated
  // squaring. This wave's tile: rows ti*128+wr*64.., cols tj*128+wc*64..
  const int tj = bsel ? t1 : t0;
  const float sgn = ((ti < 4) == (tj < 4)) ? 1.f : -1.f;
  const float wgt = ((ti == tj) ? 1.f : 2.f) * ((t0 == t1) ? 0.5f : 1.f);
  const float scale = sgn * wgt / 262144.f;   // / B^2
  const float* sqA = sq + c * kN + ti * BM + wr * 64;
  const float* sqB = sq + c * kN + tj * BM + wc * 64;

  float local = 0.f;
#pragma unroll
  for (int m = 0; m < 4; ++m) {
    float sqa_r[4];
#pragma unroll
    for (int rI = 0; rI < 4; ++rI)
      sqa_r[rI] = sqA[m * 16 + s4 * 4 + rI];
#pragma unroll
    for (int n = 0; n < 4; ++n) {
      float sqb_ = sqB[n * 16 + l15];
#pragma unroll
      for (int rI = 0; rI < 4; ++rI) {
        float L2 = sqa_r[rI] + sqb_ - 2.f * acc[m][n][rI];
        float tt = __expf(L2 * -0.0625f);  // exp(-L2/16)
        float t2 = tt * tt, t4 = t2 * t2, t8 = t4 * t4;
        local += tt + t2 + t4 + t8 + t8 * t8;
      }
    }
  }
  local *= scale;

#pragma unroll
  for (int o = 32; o > 0; o >>= 1) local += __shfl_down(local, o);
  if (lane == 0) wsum[wid] = local;
  __syncthreads();
  if (t == 0) {
    float s = 0.f;
#pragma unroll
    for (int w = 0; w < 8; ++w) s += wsum[w];
    atomicAdd(out, s);
  }
}

}  // namespace

extern "C" void kernel_launch(void* const* d_in, const int* in_sizes, int n_in,
                              void* d_out, int out_size, void* d_ws,
                              size_t ws_size, hipStream_t stream) {
  const float* src = (const float*)d_in[0];
  const float* tgt = (const float*)d_in[1];
  float* out = (float*)d_out;

  // workspace: [sq: 32*1024 f32 = 128 KiB][tot bf16: 32*1024*512*2B = 32 MiB]
  float* sq = (float*)d_ws;
  unsigned int* tot = (unsigned int*)((char*)d_ws + (size_t)kC * kN * 4);

  {
    int blocks = (kN * kC) / 4;   // one wave per (i,c) row, 4 waves/block
    prep_kernel<<<blocks, 256, 0, stream>>>(src, tgt, sq, tot, out);
  }
  {
    int blocks = NG * kC;         // 20 groups x 32 channels = 640
    mmd_kernel<<<blocks, 512, 0, stream>>>((const unsigned short*)tot, sq, out);
  }
}